// Round 10
// baseline (250.790 us; speedup 1.0000x reference)
//
#include <hip/hip_runtime.h>

// HiPPO-LegS scan — round 16: kill the per-step vmcnt(0) drain in k1/k3h.
//  * Diagnosis: mscan FETCH 28.5->8.3 MB with NO speedup; k1 at 875 GB/s vs
//    5.8 µs roofline -> all chain kernels are DRAIN-bound: __syncthreads()
//    emits s_waitcnt vmcnt(0)+s_barrier and the next-step stage is issued
//    right BEFORE it -> zero cover, full 36KB transfer exposed per step.
//  * Fix (k1 + k3h staged steps): double-buffered Ast[2]; per step:
//      B: frag/dir/x4/Bv issues -> C: vmcnt(0) [stage j, FULL-step cover]
//      -> D: lgkm-barrier -> E: issue stage j+1 -> F: MFMA on buf[j]
//      -> G: epilogue -> H: lgkm-barrier (no vmem drain).
//    Hazards: read-after-stage (C+D), re-stage-after-read (H), k1 P rows
//    wave-private, k3h S cross-wave (H lgkm barrier).
//  * mscan_s / gscan unchanged from round 15.
// Pipeline: k1(512) -> mscan_s(64) -> gscan(32) -> k3h(512). 4 launches.

#define LDK 136   // f16 k-stride of LDS state rows
#define PKF 11264 // f16 per packed triangular matrix (22528 B)

using f16 = _Float16;
typedef __attribute__((ext_vector_type(8))) f16 f16x8;
typedef __attribute__((ext_vector_type(4))) f16 f16x4;
typedef __attribute__((ext_vector_type(4))) float f32x4;

__device__ __forceinline__ f32x4 mfma3(f16x8 ah, f16x8 al, f16x8 bh, f16x8 bl,
                                       f32x4 c) {
  c = __builtin_amdgcn_mfma_f32_16x16x32_f16(ah, bh, c, 0, 0, 0);
  c = __builtin_amdgcn_mfma_f32_16x16x32_f16(ah, bl, c, 0, 0, 0);
  c = __builtin_amdgcn_mfma_f32_16x16x32_f16(al, bh, c, 0, 0, 0);
  return c;
}

__device__ __forceinline__ void split8(const float* v, f16x8& h, f16x8& l) {
#pragma unroll
  for (int j = 0; j < 8; ++j) {
    const float x = v[j];
    const f16 hh = (f16)x;
    h[j] = hh;
    l[j] = (f16)(x - (float)hh);
  }
}

// global m-tile owned by (h, slot): h=0 -> {0,7,1,6}, h=1 -> {2,5,3,4}
__device__ __forceinline__ int slot2mt(int h, int slot) {
  if (h == 0) return (slot & 1) ? 7 - (slot >> 1) : (slot >> 1);
  return (slot & 1) ? 5 - (slot >> 1) : 2 + (slot >> 1);
}

__device__ __forceinline__ void gload_lds16(const float* g, float* l) {
  __builtin_amdgcn_global_load_lds(
      (const __attribute__((address_space(1))) unsigned int*)g,
      (__attribute__((address_space(3))) unsigned int*)l, 16, 0, 0);
}

// barrier WITHOUT vmem drain: LDS-ordering only (rule #18 fencing)
__device__ __forceinline__ void bar_nodrain() {
  __builtin_amdgcn_sched_barrier(0);
  asm volatile("s_waitcnt lgkmcnt(0)" ::: "memory");
  __builtin_amdgcn_s_barrier();
  __builtin_amdgcn_sched_barrier(0);
}
// drain all outstanding vmem (stage + dirs); placed where cover is full-step
__device__ __forceinline__ void wait_vm0() {
  __builtin_amdgcn_sched_barrier(0);
  asm volatile("s_waitcnt vmcnt(0)" ::: "memory");
  __builtin_amdgcn_sched_barrier(0);
}

// ---------------------------------------------------------------------------
// Packed triangular matrix staging (f16) — mscan/gscan (unchanged).
__device__ __forceinline__ int pk_src_off(int m) {
  int b, local, ccm1, sh;
  if (m < 128)      { b = 0; local = m;       ccm1 = 3;  sh = 2; }
  else if (m < 384) { b = 1; local = m - 128; ccm1 = 7;  sh = 3; }
  else if (m < 896) { b = 2; local = m - 384; ccm1 = 15; sh = 4; }
  else              { b = 3; local = m - 896; ccm1 = 15; sh = 4; }
  const int ri = local >> sh, cp = local & ccm1;
  const int c = cp ^ (ri & ccm1);
  return (b * 32 + ri) * 128 + c * 8;
}

__device__ __forceinline__ void read_pk(const f16* __restrict__ Bs, int nt,
                                        int lr, int j0, f16x8& v) {
  const int b = nt >> 1;
  const int ri = ((nt & 1) << 4) + lr;
  const int ccm1 = (b == 0) ? 3 : (b == 1) ? 7 : 15;
  const int fb = (b == 0) ? 0 : (b == 1) ? 1024 : (b == 2) ? 3072 : 7168;
  const int c = j0 ^ (ri & ccm1);
  v = *(const f16x8*)(Bs + fb + ri * ((ccm1 + 1) * 8) + c * 8);
}

template <int NT, int IT>
__device__ __forceinline__ void pk_precompute(int tid, int (&src)[IT]) {
#pragma unroll
  for (int it = 0; it < IT; ++it) {
    const int m = tid + it * NT;
    src[it] = (m < 1408) ? pk_src_off(m) : 0;
  }
}

template <int NT, int IT>
__device__ __forceinline__ void pk_stage(const f16* __restrict__ gMh,
                                         const f16* __restrict__ gMl,
                                         f16* __restrict__ dH,
                                         f16* __restrict__ dL,
                                         const int (&src)[IT], int tid) {
#pragma unroll
  for (int it = 0; it < IT; ++it) {
    const int m = tid + it * NT;
    if (m < 1408) {
      gload_lds16((const float*)(gMh + src[it]), (float*)(dH + m * 8));
      gload_lds16((const float*)(gMl + src[it]), (float*)(dL + m * 8));
    }
  }
}

// ---------------------------------------------------------------------------
// Staged-A layout for k1/k3h (f32, LDS, 9216 floats = 36 KB).
__device__ __forceinline__ void compute_soff(int tid, int (&soff)[8]) {
#pragma unroll
  for (int it = 0; it < 8; ++it) {
    const int m = tid + it * 320;
    if (m < 2304) {
      const int kt = (m >= 768) + (m >= 1536) + (m >= 2048);
      const int local = m - ((kt >= 1) * 768 + (kt >= 2) * 768 + (kt >= 3) * 512);
      const int rp = local >> 3, c = local & 7;
      const int r = rp + 32 + (kt >= 2) * 32 + (kt >= 3) * 32;
      soff[it] = r * 128 + kt * 32 + ((c ^ (rp & 7)) << 2);
    } else {
      soff[it] = 0;
    }
  }
}

__device__ __forceinline__ void issue_A(const float* __restrict__ Al,
                                        float* __restrict__ Ast,
                                        const int (&soff)[8], int tid) {
#pragma unroll
  for (int it = 0; it < 8; ++it) {
    if (it < 7 || tid < 64)
      gload_lds16(Al + soff[it], Ast + (tid + it * 320) * 4);
  }
}

__device__ __forceinline__ void read_staged(const float* __restrict__ Ast,
                                            int nt, int kt, int lr, int q,
                                            f16x8& ch, f16x8& cl) {
  const int rp = nt * 16 + lr - (32 + (kt >= 2) * 32 + (kt >= 3) * 32);
  const float* pb =
      Ast + ((kt >= 1) * 3072 + (kt >= 2) * 3072 + (kt >= 3) * 2048) + rp * 32;
  float raw[8];
  *(float4*)&raw[0] = *(const float4*)(pb + (((2 * q + 0) ^ (rp & 7)) << 2));
  *(float4*)&raw[4] = *(const float4*)(pb + (((2 * q + 1) ^ (rp & 7)) << 2));
  split8(raw, ch, cl);
}

// ---------------------------------------------------------------------------
// chain_step_k1a: async-pipelined k1 step. Phases B..H (see header comment).
// P rows are wave-private (wave wv owns rows wv*16..+15).
__device__ __forceinline__ void chain_step_k1a(const float* __restrict__ Acur,
                                               const float* __restrict__ Anext,
                                               const float* __restrict__ x32,
                                               const float* __restrict__ Bvl,
                                               f16* __restrict__ Ph,
                                               f16* __restrict__ Pl,
                                               const float* __restrict__ AstCur,
                                               float* __restrict__ AstNxt,
                                               const int (&soff)[8],
                                               int wv, int mt) {
  const int tid = threadIdx.x;
  const int lane = tid & 63, lr = lane & 15, q = lane >> 4;
  const bool wrow = (mt >= 8);
  const int ktA0 = wrow ? 0 : (mt >> 1);
  // --- B: frag loads (own rows) + early global issues ---
  f16x8 ah[4], al[4];
#pragma unroll
  for (int kt = 0; kt < 4; ++kt) {
    if (kt >= ktA0) {
      const int off = (wv * 16 + lr) * LDK + kt * 32 + q * 8;
      ah[kt] = *(const f16x8*)(Ph + off);
      al[kt] = *(const f16x8*)(Pl + off);
    }
  }
  const bool need0 = wrow || mt == 0;
  const bool need1 = wrow || mt <= 1;
  float dir0[8], dir1[8];
  if (need0) {
    const float* p = Acur + lr * 128 + q * 8;
    *(float4*)&dir0[0] = *(const float4*)p;
    *(float4*)&dir0[4] = *(const float4*)(p + 4);
  }
  if (need1) {
    const float* p = Acur + (16 + lr) * 128 + q * 8;
    *(float4*)&dir1[0] = *(const float4*)p;
    *(float4*)&dir1[4] = *(const float4*)(p + 4);
  }
  float4 x4v = {0.f, 0.f, 0.f, 0.f};
  float bnv[8];
  if (wrow) {
    const int b0 = (mt - 8) * 16 + q * 4;
    x4v = *(const float4*)(x32 + b0);
#pragma unroll
    for (int nt = 0; nt < 8; ++nt) bnv[nt] = Bvl[nt * 16 + lr];
  }
  // --- C+D: stage(j) complete across all waves ---
  wait_vm0();
  bar_nodrain();
  // --- E: issue stage(j+1) (buffer last read 2 steps ago; stays in flight) ---
  if (Anext) issue_A(Anext, AstNxt, soff, tid);
  // --- F: compute ---
  f32x4 acc[8];
#pragma unroll
  for (int nt = 0; nt < 8; ++nt) acc[nt] = (f32x4){0.f, 0.f, 0.f, 0.f};
#pragma unroll
  for (int nt = 2; nt < 8; ++nt) {
    if (wrow || nt >= mt) {
#pragma unroll
      for (int kt = 0; kt < 4; ++kt) {
        if (kt >= ktA0 && kt <= (nt >> 1)) {
          f16x8 ch, cl;
          read_staged(AstCur, nt, kt, lr, q, ch, cl);
          acc[nt] = mfma3(ah[kt], al[kt], ch, cl, acc[nt]);
        }
      }
    }
  }
  if (need0) {
    f16x8 ch, cl;
    split8(dir0, ch, cl);
    acc[0] = mfma3(ah[0], al[0], ch, cl, acc[0]);
  }
  if (need1) {
    f16x8 ch, cl;
    split8(dir1, ch, cl);
    acc[1] = mfma3(ah[0], al[0], ch, cl, acc[1]);
  }
  // --- G: epilogue (own rows; wrow data already in regs) ---
#pragma unroll
  for (int nt = 0; nt < 8; ++nt) {
    if (!(wrow || nt >= mt)) continue;
    float v[4] = {acc[nt][0], acc[nt][1], acc[nt][2], acc[nt][3]};
    if (wrow) {
      v[0] += bnv[nt] * x4v.x; v[1] += bnv[nt] * x4v.y;
      v[2] += bnv[nt] * x4v.z; v[3] += bnv[nt] * x4v.w;
    }
#pragma unroll
    for (int r = 0; r < 4; ++r) {
      const int o = (wv * 16 + q * 4 + r) * LDK + nt * 16 + lr;
      const f16 hh = (f16)v[r];
      Ph[o] = hh;
      Pl[o] = (f16)(v[r] - (float)hh);
    }
  }
  // --- H: wave alignment (no vmem drain; stage(j+1) stays in flight) ---
  bar_nodrain();
}

// copy P' out as PLAIN M (f16 hi/lo) + w (f32 [n][32]); triangular-gated. (k1)
__device__ __forceinline__ void chain_copyout(const f16* __restrict__ Ph,
                                              const f16* __restrict__ Pl, int h,
                                              f16* __restrict__ oMh,
                                              f16* __restrict__ oMl,
                                              float* __restrict__ oW) {
  const int tid = threadIdx.x;
  for (int t = tid; t < 1024; t += 320) {
    const int i = t >> 3;
    const int slot = (t >> 1) & 3;
    const int half = t & 1;
    const int mtg = slot2mt(h, slot);
    const int y0 = mtg * 16 + half * 8;
    if ((y0 >> 5) > (i >> 5)) continue;  // zero tile: skip store
    f16x8 hv, lv;
#pragma unroll
    for (int e = 0; e < 8; ++e) {
      hv[e] = Ph[(slot * 16 + half * 8 + e) * LDK + i];
      lv[e] = Pl[(slot * 16 + half * 8 + e) * LDK + i];
    }
    *(f16x8*)(oMh + i * 128 + y0) = hv;
    *(f16x8*)(oMl + i * 128 + y0) = lv;
  }
  for (int t = tid; t < 512; t += 320) {
    const int n = t >> 2, b4 = (t & 3) * 4;
    float4 o;
    float* po = (float*)&o;
#pragma unroll
    for (int e = 0; e < 4; ++e)
      po[e] = (float)Ph[(64 + b4 + e) * LDK + n] + (float)Pl[(64 + b4 + e) * LDK + n];
    *(float4*)(oW + n * 32 + h * 16 + b4) = o;
  }
}

// ---------------------------------------------------------------------------
// state_step_h_b16: 16-row state <- state * B^T (+w add), B from global. (k3h)
__device__ __forceinline__ void state_step_h_b16(const f16* __restrict__ Bh16,
                                                 const f16* __restrict__ Bl16,
                                                 const float* __restrict__ aux0,
                                                 f16* __restrict__ Sh,
                                                 f16* __restrict__ Sl, int h) {
  const int tid = threadIdx.x;
  const int wv4 = tid >> 6;
  const bool act = (wv4 < 4);
  const int wv = wv4 & 3;
  const int lane = tid & 63, lr = lane & 15, q = lane >> 4;
  const int nts[2] = {wv, 7 - wv};
  const int ktAmax = (7 - wv) >> 1;
  f16x8 ah[4], al[4];
  f16x8 bh[2][4], bl[2][4];
  f32x4 acc[2];
  if (act) {
#pragma unroll
    for (int kt = 0; kt < 4; ++kt)
      if (kt <= ktAmax) {
        const int off = lr * LDK + kt * 32 + q * 8;
        ah[kt] = *(const f16x8*)(Sh + off);
        al[kt] = *(const f16x8*)(Sl + off);
      }
#pragma unroll
    for (int ni = 0; ni < 2; ++ni) {
      const int nt = nts[ni];
#pragma unroll
      for (int kt = 0; kt < 4; ++kt)
        if (kt <= (nt >> 1)) {
          const int o = (nt * 16 + lr) * 128 + kt * 32 + q * 8;
          bh[ni][kt] = *(const f16x8*)(Bh16 + o);
          bl[ni][kt] = *(const f16x8*)(Bl16 + o);
        }
    }
#pragma unroll
    for (int ni = 0; ni < 2; ++ni) acc[ni] = (f32x4){0.f, 0.f, 0.f, 0.f};
#pragma unroll
    for (int ni = 0; ni < 2; ++ni) {
      const int nt = nts[ni];
#pragma unroll
      for (int kt = 0; kt < 4; ++kt)
        if (kt <= (nt >> 1))
          acc[ni] = mfma3(ah[kt], al[kt], bh[ni][kt], bl[ni][kt], acc[ni]);
    }
  }
  __syncthreads();
  if (act) {
#pragma unroll
    for (int ni = 0; ni < 2; ++ni) {
      const int nt = nts[ni];
      float v[4] = {acc[ni][0], acc[ni][1], acc[ni][2], acc[ni][3]};
      const int bq = q * 4;
      const float4 w4 = *(const float4*)(aux0 + (nt * 16 + lr) * 32 + h * 16 + bq);
      v[0] += w4.x; v[1] += w4.y; v[2] += w4.z; v[3] += w4.w;
#pragma unroll
      for (int r = 0; r < 4; ++r) {
        const int o = (bq + r) * LDK + nt * 16 + lr;
        const f16 hh = (f16)v[r];
        Sh[o] = hh;
        Sl[o] = (f16)(v[r] - (float)hh);
      }
    }
  }
  __syncthreads();
}

// state_step_h_stagedA: async-pipelined k3h replay step (phases B..H).
// S is cross-wave: frag reads all rows, epilogue writes own columns.
__device__ __forceinline__ void state_step_h_stagedA(
    const float* __restrict__ Acur, const float* __restrict__ Anext,
    const float* __restrict__ x32, const float* __restrict__ Bvl,
    f16* __restrict__ Sh, f16* __restrict__ Sl, float* __restrict__ outp,
    int h, const float* __restrict__ AstCur, float* __restrict__ AstNxt,
    const int (&soff)[8]) {
  const int tid = threadIdx.x;
  const int wv4 = tid >> 6;
  const bool act = (wv4 < 4);
  const int wv = wv4 & 3;
  const int lane = tid & 63, lr = lane & 15, q = lane >> 4;
  const int ntL = wv, ntH = 7 - wv;
  // --- B: frag loads + early global issues ---
  f16x8 ah[4], al[4];
  float dir[8];
  float4 x4v = {0.f, 0.f, 0.f, 0.f};
  float bnL = 0.f, bnH = 0.f;
  if (act) {
    const int ktAmax = ntH >> 1;
#pragma unroll
    for (int kt = 0; kt < 4; ++kt)
      if (kt <= ktAmax) {
        const int off = lr * LDK + kt * 32 + q * 8;
        ah[kt] = *(const f16x8*)(Sh + off);
        al[kt] = *(const f16x8*)(Sl + off);
      }
    if (wv < 2) {
      const float* p = Acur + (ntL * 16 + lr) * 128 + q * 8;
      *(float4*)&dir[0] = *(const float4*)p;
      *(float4*)&dir[4] = *(const float4*)(p + 4);
    }
    x4v = *(const float4*)(x32 + h * 16 + q * 4);
    bnL = Bvl[ntL * 16 + lr];
    bnH = Bvl[ntH * 16 + lr];
  }
  // --- C+D: stage complete across all waves ---
  wait_vm0();
  bar_nodrain();
  // --- E: issue next stage ---
  if (Anext) issue_A(Anext, AstNxt, soff, tid);
  // --- F: compute ---
  f32x4 accL = (f32x4){0.f, 0.f, 0.f, 0.f}, accH = accL;
  if (act) {
#pragma unroll
    for (int kt = 0; kt < 4; ++kt) {
      if (kt <= (ntH >> 1)) {
        f16x8 ch, cl;
        read_staged(AstCur, ntH, kt, lr, q, ch, cl);
        accH = mfma3(ah[kt], al[kt], ch, cl, accH);
      }
    }
    if (wv >= 2) {
#pragma unroll
      for (int kt = 0; kt < 4; ++kt) {
        if (kt <= (ntL >> 1)) {
          f16x8 ch, cl;
          read_staged(AstCur, ntL, kt, lr, q, ch, cl);
          accL = mfma3(ah[kt], al[kt], ch, cl, accL);
        }
      }
    } else {
      f16x8 ch, cl;
      split8(dir, ch, cl);
      accL = mfma3(ah[0], al[0], ch, cl, accL);
    }
  }
  // --- G: epilogue (writes own columns across all rows; out stores) ---
  if (act) {
#pragma unroll
    for (int ni = 0; ni < 2; ++ni) {
      const int nt = (ni == 0) ? ntL : ntH;
      const float bn = (ni == 0) ? bnL : bnH;
      const f32x4 a = (ni == 0) ? accL : accH;
      float v[4] = {a[0], a[1], a[2], a[3]};
      const int bq = q * 4;
      v[0] += bn * x4v.x; v[1] += bn * x4v.y;
      v[2] += bn * x4v.z; v[3] += bn * x4v.w;
      if (outp) {
#pragma unroll
        for (int r = 0; r < 4; ++r)
          outp[(h * 16 + bq + r) * 128 + nt * 16 + lr] = v[r];
      }
#pragma unroll
      for (int r = 0; r < 4; ++r) {
        const int o = (bq + r) * LDK + nt * 16 + lr;
        const f16 hh = (f16)v[r];
        Sh[o] = hh;
        Sl[o] = (f16)(v[r] - (float)hh);
      }
    }
  }
  // --- H: cross-wave S visibility (lgkm only; stage stays in flight) ---
  bar_nodrain();
}

// ---------------------------------------------------------------------------
// K1: chunk units. grid 512 (c = bid>>1, h = bid&1), 320 threads. writes set A.
// Async pipeline: Ast[2] double-buffer, no per-step vmem drain.
__global__ __launch_bounds__(320) void k1_chunks(const float* __restrict__ A,
                                                 const float* __restrict__ x,
                                                 const float* __restrict__ Bv,
                                                 f16* __restrict__ Mh,
                                                 f16* __restrict__ Ml,
                                                 float* __restrict__ Wf) {
  __shared__ f16 Ph[80 * LDK], Pl[80 * LDK];
  __shared__ float Ast[2][9216];
  const int tid = threadIdx.x;
  const int c = blockIdx.x >> 1, h = blockIdx.x & 1;
  const int l0 = 4 * c;
  int soff[8];
  compute_soff(tid, soff);
  issue_A(A + (size_t)(l0 + 1) * 16384, Ast[1], soff, tid);  // stage step1 -> buf1
  const float* A0 = A + (size_t)l0 * 16384;
  for (int t = tid; t < 2048; t += 320) {
    const int k = t >> 4, u = t & 15;
    const int slot = u >> 2, fo = (u & 3) * 4;
    const int mtg = slot2mt(h, slot);
    const int y = mtg * 16 + fo;
    float vv[4];
    if ((y >> 5) <= (k >> 5)) {
      const float4 v = *(const float4*)(A0 + k * 128 + y);
      vv[0] = v.x; vv[1] = v.y; vv[2] = v.z; vv[3] = v.w;
    } else {
      vv[0] = vv[1] = vv[2] = vv[3] = 0.f;
    }
#pragma unroll
    for (int e = 0; e < 4; ++e) {
      const f16 hh = (f16)vv[e];
      Ph[(slot * 16 + fo + e) * LDK + k] = hh;
      Pl[(slot * 16 + fo + e) * LDK + k] = (f16)(vv[e] - (float)hh);
    }
  }
  for (int t = tid; t < 512; t += 320) {
    const int b = t >> 5, n4 = (t & 31) * 4;
    const float xb = x[l0 * 32 + h * 16 + b];
#pragma unroll
    for (int e = 0; e < 4; ++e) {
      const float u = xb * Bv[l0 * 128 + n4 + e];
      const f16 hh = (f16)u;
      Ph[(64 + b) * LDK + n4 + e] = hh;
      Pl[(64 + b) * LDK + n4 + e] = (f16)(u - (float)hh);
    }
  }
  bar_nodrain();  // init P visible (stage1 still in flight; drained in step1 C)
  const int wv = tid >> 6;
  const int mt = (wv == 4) ? (8 + h) : slot2mt(h, wv);
  // step1: cur=buf1, next->buf0; step2: cur=buf0, next->buf1; step3: cur=buf1
  chain_step_k1a(A + (size_t)(l0 + 1) * 16384, A + (size_t)(l0 + 2) * 16384,
                 x + (l0 + 1) * 32, Bv + (l0 + 1) * 128, Ph, Pl,
                 Ast[1], Ast[0], soff, wv, mt);
  chain_step_k1a(A + (size_t)(l0 + 2) * 16384, A + (size_t)(l0 + 3) * 16384,
                 x + (l0 + 2) * 32, Bv + (l0 + 2) * 128, Ph, Pl,
                 Ast[0], Ast[1], soff, wv, mt);
  chain_step_k1a(A + (size_t)(l0 + 3) * 16384, nullptr,
                 x + (l0 + 3) * 32, Bv + (l0 + 3) * 128, Ph, Pl,
                 Ast[1], Ast[0], soff, wv, mt);
  chain_copyout(Ph, Pl, h, Mh + (size_t)c * 16384, Ml + (size_t)c * 16384,
                Wf + (size_t)c * 4096);
}

// ---------------------------------------------------------------------------
// mscan_s: within-group matrix prefix scan (unchanged from round 15).
// grid 64: g = bid&15, unit = bid>>4 (spatial stage-siblings share XCD L2).
__global__ __launch_bounds__(192) void mscan_s(const f16* __restrict__ MhA,
                                               const f16* __restrict__ MlA,
                                               const float* __restrict__ WA,
                                               f16* __restrict__ MhB,
                                               f16* __restrict__ MlB,
                                               float* __restrict__ WB) {
  __shared__ f16 Ph[48 * LDK], Pl[48 * LDK];
  __shared__ f16 BstH[2][PKF], BstL[2][PKF];
  const int bid = blockIdx.x;
  const int g = bid & 15, unit = bid >> 4;
  const int h = unit >> 1, half = unit & 1;
  const int tid = threadIdx.x;
  const int wv = tid >> 6;
  const int lane = tid & 63, lr = lane & 15, q = lane >> 4;
  const bool isW = (half == 0 && wv == 2);
  const bool isM = (wv < 2);
  const int mt = isW ? (8 + h) : (isM ? slot2mt(h, half * 2 + wv) : 0);
  const int lw = wv * 16;
  const int ktA0 = isW ? 0 : (mt >> 1);
  const size_t n0 = (size_t)(16 * g);

  int src[8];
  pk_precompute<192, 8>(tid, src);
  pk_stage<192, 8>(MhA + (n0 + 1) * 16384, MlA + (n0 + 1) * 16384,
                   BstH[1], BstL[1], src, tid);
  if (isM) {
    const f16* pMh = MhA + n0 * 16384;
    const f16* pMl = MlA + n0 * 16384;
#pragma unroll
    for (int it = 0; it < 4; ++it) {
      const int t = lane + it * 64;
      const int k = t >> 1, hk = t & 1;
      const int y0 = mt * 16 + hk * 8;
      f16x8 hv, lv;
      if ((y0 >> 5) <= (k >> 5)) {
        hv = *(const f16x8*)(pMh + k * 128 + y0);
        lv = *(const f16x8*)(pMl + k * 128 + y0);
      } else {
#pragma unroll
        for (int e = 0; e < 8; ++e) { hv[e] = (f16)0.f; lv[e] = (f16)0.f; }
      }
#pragma unroll
      for (int e = 0; e < 8; ++e) {
        Ph[(lw + hk * 8 + e) * LDK + k] = hv[e];
        Pl[(lw + hk * 8 + e) * LDK + k] = lv[e];
      }
    }
  } else if (isW) {
    const float* pW = WA + n0 * 4096;
#pragma unroll
    for (int it = 0; it < 8; ++it) {
      const int t = lane + it * 64;
      const int n = t >> 2, b4 = (t & 3) * 4;
      const float4 w4 = *(const float4*)(pW + n * 32 + h * 16 + b4);
      const float vv[4] = {w4.x, w4.y, w4.z, w4.w};
#pragma unroll
      for (int r = 0; r < 4; ++r) {
        const f16 hh = (f16)vv[r];
        Ph[(lw + b4 + r) * LDK + n] = hh;
        Pl[(lw + b4 + r) * LDK + n] = (f16)(vv[r] - (float)hh);
      }
    }
  }
  __syncthreads();

#pragma unroll 1
  for (int j = 1; j <= 15; ++j) {
    const size_t nd = n0 + j;
    const int cur = j & 1;
    if (j < 15)
      pk_stage<192, 8>(MhA + (nd + 1) * 16384, MlA + (nd + 1) * 16384,
                       BstH[cur ^ 1], BstL[cur ^ 1], src, tid);
    float4 w4s[8];
    if (isW) {
      const float* Wn = WA + nd * 4096;
#pragma unroll
      for (int nt = 0; nt < 8; ++nt)
        w4s[nt] = *(const float4*)(Wn + (nt * 16 + lr) * 32 + h * 16 + q * 4);
    }
    f16x8 ah[4], al[4];
    if (isM || isW) {
#pragma unroll
      for (int kt = 0; kt < 4; ++kt)
        if (kt >= ktA0) {
          const int off = (lw + lr) * LDK + kt * 32 + q * 8;
          ah[kt] = *(const f16x8*)(Ph + off);
          al[kt] = *(const f16x8*)(Pl + off);
        }
    }
    f32x4 acc[8];
#pragma unroll
    for (int nt = 0; nt < 8; ++nt) acc[nt] = (f32x4){0.f, 0.f, 0.f, 0.f};
    if (isM || isW) {
      const int ntF = isW ? 0 : mt;
#pragma unroll
      for (int nt = 0; nt < 8; ++nt) {
        if (nt >= ntF) {
#pragma unroll
          for (int kt = 0; kt < 4; ++kt) {
            if (kt >= ktA0 && kt <= (nt >> 1)) {
              f16x8 bh, bl;
              const int j0 = kt * 4 + q;
              read_pk(BstH[cur], nt, lr, j0, bh);
              read_pk(BstL[cur], nt, lr, j0, bl);
              acc[nt] = mfma3(ah[kt], al[kt], bh, bl, acc[nt]);
            }
          }
        }
      }
    }
    if (isM) {
      f16* oMh = MhB + nd * 16384;
      f16* oMl = MlB + nd * 16384;
      if (mt & 1) {
        const int k = (mt - 1) * 16 + lr;
        const f16x4 z = {(f16)0.f, (f16)0.f, (f16)0.f, (f16)0.f};
        *(f16x4*)(oMh + k * 128 + mt * 16 + q * 4) = z;
        *(f16x4*)(oMl + k * 128 + mt * 16 + q * 4) = z;
      }
#pragma unroll
      for (int nt = 0; nt < 8; ++nt) {
        if (nt < mt) continue;
        f16x4 hv4, lv4;
#pragma unroll
        for (int r = 0; r < 4; ++r) {
          const float v = acc[nt][r];
          const f16 hh = (f16)v;
          const f16 ll = (f16)(v - (float)hh);
          hv4[r] = hh;
          lv4[r] = ll;
          Ph[(lw + q * 4 + r) * LDK + nt * 16 + lr] = hh;
          Pl[(lw + q * 4 + r) * LDK + nt * 16 + lr] = ll;
        }
        const int k = nt * 16 + lr;
        *(f16x4*)(oMh + k * 128 + mt * 16 + q * 4) = hv4;
        *(f16x4*)(oMl + k * 128 + mt * 16 + q * 4) = lv4;
      }
    } else if (isW) {
      float* oW = WB + nd * 4096;
#pragma unroll
      for (int nt = 0; nt < 8; ++nt) {
        float v[4];
#pragma unroll
        for (int r = 0; r < 4; ++r) v[r] = acc[nt][r];
        v[0] += w4s[nt].x; v[1] += w4s[nt].y; v[2] += w4s[nt].z; v[3] += w4s[nt].w;
#pragma unroll
        for (int r = 0; r < 4; ++r) {
          const f16 hh = (f16)v[r];
          Ph[(lw + q * 4 + r) * LDK + nt * 16 + lr] = hh;
          Pl[(lw + q * 4 + r) * LDK + nt * 16 + lr] = (f16)(v[r] - (float)hh);
        }
        const float4 o = {v[0], v[1], v[2], v[3]};
        *(float4*)(oW + (nt * 16 + lr) * 32 + h * 16 + q * 4) = o;
      }
    }
    __syncthreads();
  }
}

// ---------------------------------------------------------------------------
// gscan: serial Horner state scan over group totals (unchanged from round 15).
__global__ __launch_bounds__(256) void gscan(const f16* __restrict__ MhB,
                                             const f16* __restrict__ MlB,
                                             const float* __restrict__ WB,
                                             float* __restrict__ Ef) {
  __shared__ f16 Sh[16 * LDK], Sl[16 * LDK];
  __shared__ f16 GstH[2][PKF], GstL[2][PKF];
  const int g = blockIdx.x & 15, h = blockIdx.x >> 4;
  const int tid = threadIdx.x;
  int src[6];
  pk_precompute<256, 6>(tid, src);
  for (int t = tid; t < 16 * LDK; t += 256) { Sh[t] = (f16)0.f; Sl[t] = (f16)0.f; }
  if (g > 0)
    pk_stage<256, 6>(MhB + (size_t)15 * 16384, MlB + (size_t)15 * 16384,
                     GstH[0], GstL[0], src, tid);
  __syncthreads();
  const int wv = (tid >> 6) & 3;
  const int lane = tid & 63, lr = lane & 15, q = lane >> 4;
  const int nts[2] = {wv, 7 - wv};
  const int ktAmax = (7 - wv) >> 1;
#pragma unroll 1
  for (int t = 0; t < g; ++t) {
    const size_t nd = (size_t)(16 * t + 15);
    const int cur = t & 1;
    if (t + 1 < g) {
      const size_t nn = (size_t)(16 * (t + 1) + 15);
      pk_stage<256, 6>(MhB + nn * 16384, MlB + nn * 16384,
                       GstH[cur ^ 1], GstL[cur ^ 1], src, tid);
    }
    const float* aux0 = WB + nd * 4096;
    float4 w4s[2];
#pragma unroll
    for (int ni = 0; ni < 2; ++ni)
      w4s[ni] = *(const float4*)(aux0 + (nts[ni] * 16 + lr) * 32 + h * 16 + q * 4);
    f16x8 ah[4], al[4];
#pragma unroll
    for (int kt = 0; kt < 4; ++kt)
      if (kt <= ktAmax) {
        const int off = lr * LDK + kt * 32 + q * 8;
        ah[kt] = *(const f16x8*)(Sh + off);
        al[kt] = *(const f16x8*)(Sl + off);
      }
    f32x4 acc[2];
#pragma unroll
    for (int ni = 0; ni < 2; ++ni) acc[ni] = (f32x4){0.f, 0.f, 0.f, 0.f};
#pragma unroll
    for (int ni = 0; ni < 2; ++ni) {
      const int nt = nts[ni];
#pragma unroll
      for (int kt = 0; kt < 4; ++kt)
        if (kt <= (nt >> 1)) {
          f16x8 bh, bl;
          const int j0 = kt * 4 + q;
          read_pk(GstH[cur], nt, lr, j0, bh);
          read_pk(GstL[cur], nt, lr, j0, bl);
          acc[ni] = mfma3(ah[kt], al[kt], bh, bl, acc[ni]);
        }
    }
    __syncthreads();
#pragma unroll
    for (int ni = 0; ni < 2; ++ni) {
      const int nt = nts[ni];
      float v[4] = {acc[ni][0], acc[ni][1], acc[ni][2], acc[ni][3]};
      v[0] += w4s[ni].x; v[1] += w4s[ni].y; v[2] += w4s[ni].z; v[3] += w4s[ni].w;
#pragma unroll
      for (int r = 0; r < 4; ++r) {
        const int o = (q * 4 + r) * LDK + nt * 16 + lr;
        const f16 hh = (f16)v[r];
        Sh[o] = hh;
        Sl[o] = (f16)(v[r] - (float)hh);
      }
    }
    __syncthreads();
  }
  for (int t = tid; t < 2048; t += 256) {
    const int row = t & 15, n = t >> 4;
    Ef[(size_t)g * 4096 + n * 32 + h * 16 + row] =
        (float)Sh[row * LDK + n] + (float)Sl[row * LDK + n];
  }
}

// ---------------------------------------------------------------------------
// K3 h-split: grid 512 (c = bid>>1, h = bid&1), 320 thr. Async Ast[2] pipeline.
__global__ __launch_bounds__(320) void k3h(const float* __restrict__ A,
                                           const float* __restrict__ x,
                                           const float* __restrict__ Bv,
                                           const f16* __restrict__ MhA,
                                           const f16* __restrict__ MlA,
                                           const float* __restrict__ WA,
                                           const f16* __restrict__ MhB,
                                           const f16* __restrict__ MlB,
                                           const float* __restrict__ WB,
                                           const float* __restrict__ Ef,
                                           float* __restrict__ out) {
  __shared__ f16 Sh[16 * LDK], Sl[16 * LDK];
  __shared__ float Ast[2][9216];
  const int tid = threadIdx.x;
  const int c = blockIdx.x >> 1, h = blockIdx.x & 1;
  const int g = c >> 4, j = c & 15;
  int soff[8];
  compute_soff(tid, soff);
  issue_A(A + (size_t)(4 * c) * 16384, Ast[0], soff, tid);  // stage t4=0 -> buf0
  const float* Ew = Ef + (size_t)g * 4096;
  for (int tt = tid; tt < 2048; tt += 320) {
    const int row = tt & 15, n = tt >> 4;
    const float v = Ew[n * 32 + h * 16 + row];
    const f16 hh = (f16)v;
    Sh[row * LDK + n] = hh;
    Sl[row * LDK + n] = (f16)(v - (float)hh);
  }
  bar_nodrain();  // S init visible (stage stays in flight; drained in step C)
  if (j > 0) {
    const int nd = c - 1, jp = j - 1;
    const bool inA = (jp == 0);
    const f16* mh = (inA ? MhA : MhB) + (size_t)nd * 16384;
    const f16* ml = (inA ? MlA : MlB) + (size_t)nd * 16384;
    const float* w = (inA ? WA : WB) + (size_t)nd * 4096;
    state_step_h_b16(mh, ml, w, Sh, Sl, h);
  }
#pragma unroll 1
  for (int t4 = 0; t4 < 4; ++t4) {
    const int l = 4 * c + t4;
    const float* Anext = (t4 < 3) ? A + (size_t)(l + 1) * 16384 : nullptr;
    state_step_h_stagedA(A + (size_t)l * 16384, Anext, x + l * 32,
                         Bv + l * 128, Sh, Sl, out + (size_t)l * 4096, h,
                         Ast[t4 & 1], (float*)Ast[(t4 + 1) & 1], soff);
  }
}

// ---------------------------------------------------------------------------
extern "C" void kernel_launch(void* const* d_in, const int* in_sizes, int n_in,
                              void* d_out, int out_size, void* d_ws, size_t ws_size,
                              hipStream_t stream) {
  const float* x  = (const float*)d_in[0];  // (1024, 32)
  const float* A  = (const float*)d_in[1];  // (1024, 128, 128) lower-triangular
  const float* Bv = (const float*)d_in[2];  // (1024, 128)
  float* out = (float*)d_out;               // (1024, 32, 128)

  // set A: chunk units (k1 output)
  f16* MhA = (f16*)d_ws;                    // 256*16384 f16
  f16* MlA = MhA + 256 * 16384;
  float* WA = (float*)(MlA + 256 * 16384);  // 256*4096 f32
  // set B: within-group prefixes j>=1 (mscan_s output)
  f16* MhB = (f16*)(WA + 256 * 4096);
  f16* MlB = MhB + 256 * 16384;
  float* WB = (float*)(MlB + 256 * 16384);
  // entry states (f32)
  float* Ef = WB + 256 * 4096;              // 16*4096 f32; total ~42.2 MB

  k1_chunks<<<512, 320, 0, stream>>>(A, x, Bv, MhA, MlA, WA);
  mscan_s<<<64, 192, 0, stream>>>(MhA, MlA, WA, MhB, MlB, WB);
  gscan<<<32, 256, 0, stream>>>(MhB, MlB, WB, Ef);
  k3h<<<512, 320, 0, stream>>>(A, x, Bv, MhA, MlA, WA, MhB, MlB, WB, Ef, out);
}

// Round 12
// 238.616 us; speedup vs baseline: 1.0510x; 1.0510x over previous
//
#include <hip/hip_runtime.h>

// HiPPO-LegS scan — round 18: round-17 resubmit + vmcnt-FIFO ordering fix.
//  * Round-17 failed at container level (no counters). Re-audit found a real
//    pipeline flaw: phase E issued the LDS stage BEFORE the next-step reg
//    loads (dir/x4/bn/w4n). vmcnt is FIFO -> phase G's read of those regs
//    forces a drain of the ENTIRE stage (compiler-inserted waitcnt), killing
//    the async cover. Fix: reg-destined loads issue FIRST, stage LAST, so
//    reg reads wait at vmcnt(~16) and the stage stays in flight.
//  * Applied in chain_step_k1a, state_step_h_stagedA, gscan w4n, prologues.
//  * Everything else identical to round 17 (gscan async rewrite, mscan
//    store-first epilogue, k1/k3h dir double-buffering).
// Pipeline: k1(512) -> mscan_s(64) -> gscan(32) -> k3h(512). 4 launches.

#define LDK 136   // f16 k-stride of LDS state rows
#define PKF 11264 // f16 per packed triangular matrix (22528 B)

using f16 = _Float16;
typedef __attribute__((ext_vector_type(8))) f16 f16x8;
typedef __attribute__((ext_vector_type(4))) f16 f16x4;
typedef __attribute__((ext_vector_type(4))) float f32x4;

__device__ __forceinline__ f32x4 mfma3(f16x8 ah, f16x8 al, f16x8 bh, f16x8 bl,
                                       f32x4 c) {
  c = __builtin_amdgcn_mfma_f32_16x16x32_f16(ah, bh, c, 0, 0, 0);
  c = __builtin_amdgcn_mfma_f32_16x16x32_f16(ah, bl, c, 0, 0, 0);
  c = __builtin_amdgcn_mfma_f32_16x16x32_f16(al, bh, c, 0, 0, 0);
  return c;
}

__device__ __forceinline__ void split8(const float* v, f16x8& h, f16x8& l) {
#pragma unroll
  for (int j = 0; j < 8; ++j) {
    const float x = v[j];
    const f16 hh = (f16)x;
    h[j] = hh;
    l[j] = (f16)(x - (float)hh);
  }
}

// global m-tile owned by (h, slot): h=0 -> {0,7,1,6}, h=1 -> {2,5,3,4}
__device__ __forceinline__ int slot2mt(int h, int slot) {
  if (h == 0) return (slot & 1) ? 7 - (slot >> 1) : (slot >> 1);
  return (slot & 1) ? 5 - (slot >> 1) : 2 + (slot >> 1);
}

__device__ __forceinline__ void gload_lds16(const float* g, float* l) {
  __builtin_amdgcn_global_load_lds(
      (const __attribute__((address_space(1))) unsigned int*)g,
      (__attribute__((address_space(3))) unsigned int*)l, 16, 0, 0);
}

// barrier WITHOUT vmem drain: LDS-ordering only (rule #18 fencing)
__device__ __forceinline__ void bar_nodrain() {
  __builtin_amdgcn_sched_barrier(0);
  asm volatile("s_waitcnt lgkmcnt(0)" ::: "memory");
  __builtin_amdgcn_s_barrier();
  __builtin_amdgcn_sched_barrier(0);
}
// drain all outstanding vmem; placed where cover is full-step
__device__ __forceinline__ void wait_vm0() {
  __builtin_amdgcn_sched_barrier(0);
  asm volatile("s_waitcnt vmcnt(0)" ::: "memory");
  __builtin_amdgcn_sched_barrier(0);
}

// ---------------------------------------------------------------------------
// Packed triangular matrix staging (f16) — mscan/gscan.
__device__ __forceinline__ int pk_src_off(int m) {
  int b, local, ccm1, sh;
  if (m < 128)      { b = 0; local = m;       ccm1 = 3;  sh = 2; }
  else if (m < 384) { b = 1; local = m - 128; ccm1 = 7;  sh = 3; }
  else if (m < 896) { b = 2; local = m - 384; ccm1 = 15; sh = 4; }
  else              { b = 3; local = m - 896; ccm1 = 15; sh = 4; }
  const int ri = local >> sh, cp = local & ccm1;
  const int c = cp ^ (ri & ccm1);
  return (b * 32 + ri) * 128 + c * 8;
}

__device__ __forceinline__ void read_pk(const f16* __restrict__ Bs, int nt,
                                        int lr, int j0, f16x8& v) {
  const int b = nt >> 1;
  const int ri = ((nt & 1) << 4) + lr;
  const int ccm1 = (b == 0) ? 3 : (b == 1) ? 7 : 15;
  const int fb = (b == 0) ? 0 : (b == 1) ? 1024 : (b == 2) ? 3072 : 7168;
  const int c = j0 ^ (ri & ccm1);
  v = *(const f16x8*)(Bs + fb + ri * ((ccm1 + 1) * 8) + c * 8);
}

template <int NT, int IT>
__device__ __forceinline__ void pk_precompute(int tid, int (&src)[IT]) {
#pragma unroll
  for (int it = 0; it < IT; ++it) {
    const int m = tid + it * NT;
    src[it] = (m < 1408) ? pk_src_off(m) : 0;
  }
}

template <int NT, int IT>
__device__ __forceinline__ void pk_stage(const f16* __restrict__ gMh,
                                         const f16* __restrict__ gMl,
                                         f16* __restrict__ dH,
                                         f16* __restrict__ dL,
                                         const int (&src)[IT], int tid) {
#pragma unroll
  for (int it = 0; it < IT; ++it) {
    const int m = tid + it * NT;
    if (m < 1408) {
      gload_lds16((const float*)(gMh + src[it]), (float*)(dH + m * 8));
      gload_lds16((const float*)(gMl + src[it]), (float*)(dL + m * 8));
    }
  }
}

// ---------------------------------------------------------------------------
// Staged-A layout for k1/k3h (f32, LDS, 9216 floats = 36 KB).
__device__ __forceinline__ void compute_soff(int tid, int (&soff)[8]) {
#pragma unroll
  for (int it = 0; it < 8; ++it) {
    const int m = tid + it * 320;
    if (m < 2304) {
      const int kt = (m >= 768) + (m >= 1536) + (m >= 2048);
      const int local = m - ((kt >= 1) * 768 + (kt >= 2) * 768 + (kt >= 3) * 512);
      const int rp = local >> 3, c = local & 7;
      const int r = rp + 32 + (kt >= 2) * 32 + (kt >= 3) * 32;
      soff[it] = r * 128 + kt * 32 + ((c ^ (rp & 7)) << 2);
    } else {
      soff[it] = 0;
    }
  }
}

__device__ __forceinline__ void issue_A(const float* __restrict__ Al,
                                        float* __restrict__ Ast,
                                        const int (&soff)[8], int tid) {
#pragma unroll
  for (int it = 0; it < 8; ++it) {
    if (it < 7 || tid < 64)
      gload_lds16(Al + soff[it], Ast + (tid + it * 320) * 4);
  }
}

__device__ __forceinline__ void read_staged(const float* __restrict__ Ast,
                                            int nt, int kt, int lr, int q,
                                            f16x8& ch, f16x8& cl) {
  const int rp = nt * 16 + lr - (32 + (kt >= 2) * 32 + (kt >= 3) * 32);
  const float* pb =
      Ast + ((kt >= 1) * 3072 + (kt >= 2) * 3072 + (kt >= 3) * 2048) + rp * 32;
  float raw[8];
  *(float4*)&raw[0] = *(const float4*)(pb + (((2 * q + 0) ^ (rp & 7)) << 2));
  *(float4*)&raw[4] = *(const float4*)(pb + (((2 * q + 1) ^ (rp & 7)) << 2));
  split8(raw, ch, cl);
}

// ---------------------------------------------------------------------------
// chain_step_k1a: async k1 step. Phase E issues reg-destined loads FIRST
// (dirs/x4/bn), THEN the stage -> reg reads wait at vmcnt(~16), stage flies.
__device__ __forceinline__ void chain_step_k1a(const float* __restrict__ Anext,
                                               const float* __restrict__ x32,
                                               const float* __restrict__ Bvl,
                                               f16* __restrict__ Ph,
                                               f16* __restrict__ Pl,
                                               const float* __restrict__ AstCur,
                                               float* __restrict__ AstNxt,
                                               const int (&soff)[8],
                                               int wv, int mt,
                                               float (&dir0)[8], float (&dir1)[8],
                                               const float* __restrict__ AdirNext) {
  const int tid = threadIdx.x;
  const int lane = tid & 63, lr = lane & 15, q = lane >> 4;
  const bool wrow = (mt >= 8);
  const int ktA0 = wrow ? 0 : (mt >> 1);
  const bool need0 = wrow || mt == 0;
  const bool need1 = wrow || mt <= 1;
  // --- B: frag loads (LDS only) ---
  f16x8 ah[4], al[4];
#pragma unroll
  for (int kt = 0; kt < 4; ++kt) {
    if (kt >= ktA0) {
      const int off = (wv * 16 + lr) * LDK + kt * 32 + q * 8;
      ah[kt] = *(const f16x8*)(Ph + off);
      al[kt] = *(const f16x8*)(Pl + off);
    }
  }
  // --- C+D: stage(j)+dirs(j) complete (issued one full step earlier) ---
  wait_vm0();
  bar_nodrain();
  // --- E: reg-destined loads FIRST ---
  float dirN0[8], dirN1[8];
  if (AdirNext) {
    if (need0) {
      const float* p = AdirNext + lr * 128 + q * 8;
      *(float4*)&dirN0[0] = *(const float4*)p;
      *(float4*)&dirN0[4] = *(const float4*)(p + 4);
    }
    if (need1) {
      const float* p = AdirNext + (16 + lr) * 128 + q * 8;
      *(float4*)&dirN1[0] = *(const float4*)p;
      *(float4*)&dirN1[4] = *(const float4*)(p + 4);
    }
  }
  float4 x4v = {0.f, 0.f, 0.f, 0.f};
  float bnv[8];
  if (wrow) {
    const int b0 = (mt - 8) * 16 + q * 4;
    x4v = *(const float4*)(x32 + b0);
#pragma unroll
    for (int nt = 0; nt < 8; ++nt) bnv[nt] = Bvl[nt * 16 + lr];
  }
  // --- E2: stage(j+1) LAST (stays in flight past all reg reads) ---
  if (Anext) issue_A(Anext, AstNxt, soff, tid);
  // --- F: compute ---
  f32x4 acc[8];
#pragma unroll
  for (int nt = 0; nt < 8; ++nt) acc[nt] = (f32x4){0.f, 0.f, 0.f, 0.f};
#pragma unroll
  for (int nt = 2; nt < 8; ++nt) {
    if (wrow || nt >= mt) {
#pragma unroll
      for (int kt = 0; kt < 4; ++kt) {
        if (kt >= ktA0 && kt <= (nt >> 1)) {
          f16x8 ch, cl;
          read_staged(AstCur, nt, kt, lr, q, ch, cl);
          acc[nt] = mfma3(ah[kt], al[kt], ch, cl, acc[nt]);
        }
      }
    }
  }
  if (need0) {
    f16x8 ch, cl;
    split8(dir0, ch, cl);
    acc[0] = mfma3(ah[0], al[0], ch, cl, acc[0]);
  }
  if (need1) {
    f16x8 ch, cl;
    split8(dir1, ch, cl);
    acc[1] = mfma3(ah[0], al[0], ch, cl, acc[1]);
  }
  // --- G: epilogue (own rows) ---
#pragma unroll
  for (int nt = 0; nt < 8; ++nt) {
    if (!(wrow || nt >= mt)) continue;
    float v[4] = {acc[nt][0], acc[nt][1], acc[nt][2], acc[nt][3]};
    if (wrow) {
      v[0] += bnv[nt] * x4v.x; v[1] += bnv[nt] * x4v.y;
      v[2] += bnv[nt] * x4v.z; v[3] += bnv[nt] * x4v.w;
    }
#pragma unroll
    for (int r = 0; r < 4; ++r) {
      const int o = (wv * 16 + q * 4 + r) * LDK + nt * 16 + lr;
      const f16 hh = (f16)v[r];
      Ph[o] = hh;
      Pl[o] = (f16)(v[r] - (float)hh);
    }
  }
  // rotate dir buffers (waits only for the dir loads; stage stays in flight)
  if (AdirNext) {
    if (need0) {
#pragma unroll
      for (int e = 0; e < 8; ++e) dir0[e] = dirN0[e];
    }
    if (need1) {
#pragma unroll
      for (int e = 0; e < 8; ++e) dir1[e] = dirN1[e];
    }
  }
  // --- H: wave alignment (no vmem drain) ---
  bar_nodrain();
}

// copy P' out as PLAIN M (f16 hi/lo) + w (f32 [n][32]); triangular-gated. (k1)
__device__ __forceinline__ void chain_copyout(const f16* __restrict__ Ph,
                                              const f16* __restrict__ Pl, int h,
                                              f16* __restrict__ oMh,
                                              f16* __restrict__ oMl,
                                              float* __restrict__ oW) {
  const int tid = threadIdx.x;
  for (int t = tid; t < 1024; t += 320) {
    const int i = t >> 3;
    const int slot = (t >> 1) & 3;
    const int half = t & 1;
    const int mtg = slot2mt(h, slot);
    const int y0 = mtg * 16 + half * 8;
    if ((y0 >> 5) > (i >> 5)) continue;  // zero tile: skip store
    f16x8 hv, lv;
#pragma unroll
    for (int e = 0; e < 8; ++e) {
      hv[e] = Ph[(slot * 16 + half * 8 + e) * LDK + i];
      lv[e] = Pl[(slot * 16 + half * 8 + e) * LDK + i];
    }
    *(f16x8*)(oMh + i * 128 + y0) = hv;
    *(f16x8*)(oMl + i * 128 + y0) = lv;
  }
  for (int t = tid; t < 512; t += 320) {
    const int n = t >> 2, b4 = (t & 3) * 4;
    float4 o;
    float* po = (float*)&o;
#pragma unroll
    for (int e = 0; e < 4; ++e)
      po[e] = (float)Ph[(64 + b4 + e) * LDK + n] + (float)Pl[(64 + b4 + e) * LDK + n];
    *(float4*)(oW + n * 32 + h * 16 + b4) = o;
  }
}

// ---------------------------------------------------------------------------
// state_step_h_b16: 16-row state <- state * B^T (+w add), B from global. (k3h)
__device__ __forceinline__ void state_step_h_b16(const f16* __restrict__ Bh16,
                                                 const f16* __restrict__ Bl16,
                                                 const float* __restrict__ aux0,
                                                 f16* __restrict__ Sh,
                                                 f16* __restrict__ Sl, int h) {
  const int tid = threadIdx.x;
  const int wv4 = tid >> 6;
  const bool act = (wv4 < 4);
  const int wv = wv4 & 3;
  const int lane = tid & 63, lr = lane & 15, q = lane >> 4;
  const int nts[2] = {wv, 7 - wv};
  const int ktAmax = (7 - wv) >> 1;
  f16x8 ah[4], al[4];
  f16x8 bh[2][4], bl[2][4];
  f32x4 acc[2];
  if (act) {
#pragma unroll
    for (int kt = 0; kt < 4; ++kt)
      if (kt <= ktAmax) {
        const int off = lr * LDK + kt * 32 + q * 8;
        ah[kt] = *(const f16x8*)(Sh + off);
        al[kt] = *(const f16x8*)(Sl + off);
      }
#pragma unroll
    for (int ni = 0; ni < 2; ++ni) {
      const int nt = nts[ni];
#pragma unroll
      for (int kt = 0; kt < 4; ++kt)
        if (kt <= (nt >> 1)) {
          const int o = (nt * 16 + lr) * 128 + kt * 32 + q * 8;
          bh[ni][kt] = *(const f16x8*)(Bh16 + o);
          bl[ni][kt] = *(const f16x8*)(Bl16 + o);
        }
    }
#pragma unroll
    for (int ni = 0; ni < 2; ++ni) acc[ni] = (f32x4){0.f, 0.f, 0.f, 0.f};
#pragma unroll
    for (int ni = 0; ni < 2; ++ni) {
      const int nt = nts[ni];
#pragma unroll
      for (int kt = 0; kt < 4; ++kt)
        if (kt <= (nt >> 1))
          acc[ni] = mfma3(ah[kt], al[kt], bh[ni][kt], bl[ni][kt], acc[ni]);
    }
  }
  __syncthreads();
  if (act) {
#pragma unroll
    for (int ni = 0; ni < 2; ++ni) {
      const int nt = nts[ni];
      float v[4] = {acc[ni][0], acc[ni][1], acc[ni][2], acc[ni][3]};
      const int bq = q * 4;
      const float4 w4 = *(const float4*)(aux0 + (nt * 16 + lr) * 32 + h * 16 + bq);
      v[0] += w4.x; v[1] += w4.y; v[2] += w4.z; v[3] += w4.w;
#pragma unroll
      for (int r = 0; r < 4; ++r) {
        const int o = (bq + r) * LDK + nt * 16 + lr;
        const f16 hh = (f16)v[r];
        Sh[o] = hh;
        Sl[o] = (f16)(v[r] - (float)hh);
      }
    }
  }
  __syncthreads();
}

// state_step_h_stagedA: async k3h replay step; reg loads first, stage last.
__device__ __forceinline__ void state_step_h_stagedA(
    const float* __restrict__ Anext, const float* __restrict__ x32,
    const float* __restrict__ Bvl, f16* __restrict__ Sh, f16* __restrict__ Sl,
    float* __restrict__ outp, int h, const float* __restrict__ AstCur,
    float* __restrict__ AstNxt, const int (&soff)[8], float (&dir)[8],
    const float* __restrict__ AdirNext) {
  const int tid = threadIdx.x;
  const int wv4 = tid >> 6;
  const bool act = (wv4 < 4);
  const int wv = wv4 & 3;
  const int lane = tid & 63, lr = lane & 15, q = lane >> 4;
  const int ntL = wv, ntH = 7 - wv;
  // --- B: frag loads (LDS only) ---
  f16x8 ah[4], al[4];
  if (act) {
    const int ktAmax = ntH >> 1;
#pragma unroll
    for (int kt = 0; kt < 4; ++kt)
      if (kt <= ktAmax) {
        const int off = lr * LDK + kt * 32 + q * 8;
        ah[kt] = *(const f16x8*)(Sh + off);
        al[kt] = *(const f16x8*)(Sl + off);
      }
  }
  // --- C+D ---
  wait_vm0();
  bar_nodrain();
  // --- E: reg-destined loads FIRST ---
  float dirN[8];
  if (AdirNext && act && wv < 2) {
    const float* p = AdirNext + (ntL * 16 + lr) * 128 + q * 8;
    *(float4*)&dirN[0] = *(const float4*)p;
    *(float4*)&dirN[4] = *(const float4*)(p + 4);
  }
  float4 x4v = {0.f, 0.f, 0.f, 0.f};
  float bnL = 0.f, bnH = 0.f;
  if (act) {
    x4v = *(const float4*)(x32 + h * 16 + q * 4);
    bnL = Bvl[ntL * 16 + lr];
    bnH = Bvl[ntH * 16 + lr];
  }
  // --- E2: stage LAST ---
  if (Anext) issue_A(Anext, AstNxt, soff, tid);
  // --- F: compute ---
  f32x4 accL = (f32x4){0.f, 0.f, 0.f, 0.f}, accH = accL;
  if (act) {
#pragma unroll
    for (int kt = 0; kt < 4; ++kt) {
      if (kt <= (ntH >> 1)) {
        f16x8 ch, cl;
        read_staged(AstCur, ntH, kt, lr, q, ch, cl);
        accH = mfma3(ah[kt], al[kt], ch, cl, accH);
      }
    }
    if (wv >= 2) {
#pragma unroll
      for (int kt = 0; kt < 4; ++kt) {
        if (kt <= (ntL >> 1)) {
          f16x8 ch, cl;
          read_staged(AstCur, ntL, kt, lr, q, ch, cl);
          accL = mfma3(ah[kt], al[kt], ch, cl, accL);
        }
      }
    } else {
      f16x8 ch, cl;
      split8(dir, ch, cl);
      accL = mfma3(ah[0], al[0], ch, cl, accL);
    }
  }
  // --- G: epilogue ---
  if (act) {
#pragma unroll
    for (int ni = 0; ni < 2; ++ni) {
      const int nt = (ni == 0) ? ntL : ntH;
      const float bn = (ni == 0) ? bnL : bnH;
      const f32x4 a = (ni == 0) ? accL : accH;
      float v[4] = {a[0], a[1], a[2], a[3]};
      const int bq = q * 4;
      v[0] += bn * x4v.x; v[1] += bn * x4v.y;
      v[2] += bn * x4v.z; v[3] += bn * x4v.w;
      if (outp) {
#pragma unroll
        for (int r = 0; r < 4; ++r)
          outp[(h * 16 + bq + r) * 128 + nt * 16 + lr] = v[r];
      }
#pragma unroll
      for (int r = 0; r < 4; ++r) {
        const int o = (bq + r) * LDK + nt * 16 + lr;
        const f16 hh = (f16)v[r];
        Sh[o] = hh;
        Sl[o] = (f16)(v[r] - (float)hh);
      }
    }
  }
  if (AdirNext && act && wv < 2) {
#pragma unroll
    for (int e = 0; e < 8; ++e) dir[e] = dirN[e];
  }
  // --- H ---
  bar_nodrain();
}

// ---------------------------------------------------------------------------
// K1: chunk units. grid 512 (c = bid>>1, h = bid&1), 320 threads. writes set A.
__global__ __launch_bounds__(320) void k1_chunks(const float* __restrict__ A,
                                                 const float* __restrict__ x,
                                                 const float* __restrict__ Bv,
                                                 f16* __restrict__ Mh,
                                                 f16* __restrict__ Ml,
                                                 float* __restrict__ Wf) {
  __shared__ f16 Ph[80 * LDK], Pl[80 * LDK];
  __shared__ float Ast[2][9216];
  const int tid = threadIdx.x;
  const int c = blockIdx.x >> 1, h = blockIdx.x & 1;
  const int l0 = 4 * c;
  const int lane = tid & 63, lr = lane & 15, q = lane >> 4;
  const int wv = tid >> 6;
  const int mt = (wv == 4) ? (8 + h) : slot2mt(h, wv);
  const bool wrow = (mt >= 8);
  const bool need0 = wrow || mt == 0;
  const bool need1 = wrow || mt <= 1;
  int soff[8];
  compute_soff(tid, soff);
  // dirs for step 1 FIRST (reg-destined), then the stage
  float dir0[8], dir1[8];
  {
    const float* A1 = A + (size_t)(l0 + 1) * 16384;
    if (need0) {
      const float* p = A1 + lr * 128 + q * 8;
      *(float4*)&dir0[0] = *(const float4*)p;
      *(float4*)&dir0[4] = *(const float4*)(p + 4);
    }
    if (need1) {
      const float* p = A1 + (16 + lr) * 128 + q * 8;
      *(float4*)&dir1[0] = *(const float4*)p;
      *(float4*)&dir1[4] = *(const float4*)(p + 4);
    }
  }
  issue_A(A + (size_t)(l0 + 1) * 16384, Ast[1], soff, tid);  // stage step1 -> buf1
  const float* A0 = A + (size_t)l0 * 16384;
  for (int t = tid; t < 2048; t += 320) {
    const int k = t >> 4, u = t & 15;
    const int slot = u >> 2, fo = (u & 3) * 4;
    const int mtg = slot2mt(h, slot);
    const int y = mtg * 16 + fo;
    float vv[4];
    if ((y >> 5) <= (k >> 5)) {
      const float4 v = *(const float4*)(A0 + k * 128 + y);
      vv[0] = v.x; vv[1] = v.y; vv[2] = v.z; vv[3] = v.w;
    } else {
      vv[0] = vv[1] = vv[2] = vv[3] = 0.f;
    }
#pragma unroll
    for (int e = 0; e < 4; ++e) {
      const f16 hh = (f16)vv[e];
      Ph[(slot * 16 + fo + e) * LDK + k] = hh;
      Pl[(slot * 16 + fo + e) * LDK + k] = (f16)(vv[e] - (float)hh);
    }
  }
  for (int t = tid; t < 512; t += 320) {
    const int b = t >> 5, n4 = (t & 31) * 4;
    const float xb = x[l0 * 32 + h * 16 + b];
#pragma unroll
    for (int e = 0; e < 4; ++e) {
      const float u = xb * Bv[l0 * 128 + n4 + e];
      const f16 hh = (f16)u;
      Ph[(64 + b) * LDK + n4 + e] = hh;
      Pl[(64 + b) * LDK + n4 + e] = (f16)(u - (float)hh);
    }
  }
  bar_nodrain();  // init P visible (stage1+dirs in flight; drained at step1 C)
  chain_step_k1a(A + (size_t)(l0 + 2) * 16384, x + (l0 + 1) * 32,
                 Bv + (l0 + 1) * 128, Ph, Pl, Ast[1], Ast[0], soff, wv, mt,
                 dir0, dir1, A + (size_t)(l0 + 2) * 16384);
  chain_step_k1a(A + (size_t)(l0 + 3) * 16384, x + (l0 + 2) * 32,
                 Bv + (l0 + 2) * 128, Ph, Pl, Ast[0], Ast[1], soff, wv, mt,
                 dir0, dir1, A + (size_t)(l0 + 3) * 16384);
  chain_step_k1a(nullptr, x + (l0 + 3) * 32, Bv + (l0 + 3) * 128, Ph, Pl,
                 Ast[1], Ast[0], soff, wv, mt, dir0, dir1, nullptr);
  chain_copyout(Ph, Pl, h, Mh + (size_t)c * 16384, Ml + (size_t)c * 16384,
                Wf + (size_t)c * 4096);
}

// ---------------------------------------------------------------------------
// mscan_s: within-group matrix prefix scan (round-15 structure; epilogue
// stores issued BEFORE P-LDS writes for store-ack cover).
// grid 64: g = bid&15, unit = bid>>4 (spatial stage-siblings share XCD L2).
__global__ __launch_bounds__(192) void mscan_s(const f16* __restrict__ MhA,
                                               const f16* __restrict__ MlA,
                                               const float* __restrict__ WA,
                                               f16* __restrict__ MhB,
                                               f16* __restrict__ MlB,
                                               float* __restrict__ WB) {
  __shared__ f16 Ph[48 * LDK], Pl[48 * LDK];
  __shared__ f16 BstH[2][PKF], BstL[2][PKF];
  const int bid = blockIdx.x;
  const int g = bid & 15, unit = bid >> 4;
  const int h = unit >> 1, half = unit & 1;
  const int tid = threadIdx.x;
  const int wv = tid >> 6;
  const int lane = tid & 63, lr = lane & 15, q = lane >> 4;
  const bool isW = (half == 0 && wv == 2);
  const bool isM = (wv < 2);
  const int mt = isW ? (8 + h) : (isM ? slot2mt(h, half * 2 + wv) : 0);
  const int lw = wv * 16;
  const int ktA0 = isW ? 0 : (mt >> 1);
  const size_t n0 = (size_t)(16 * g);

  int src[8];
  pk_precompute<192, 8>(tid, src);
  pk_stage<192, 8>(MhA + (n0 + 1) * 16384, MlA + (n0 + 1) * 16384,
                   BstH[1], BstL[1], src, tid);
  if (isM) {
    const f16* pMh = MhA + n0 * 16384;
    const f16* pMl = MlA + n0 * 16384;
#pragma unroll
    for (int it = 0; it < 4; ++it) {
      const int t = lane + it * 64;
      const int k = t >> 1, hk = t & 1;
      const int y0 = mt * 16 + hk * 8;
      f16x8 hv, lv;
      if ((y0 >> 5) <= (k >> 5)) {
        hv = *(const f16x8*)(pMh + k * 128 + y0);
        lv = *(const f16x8*)(pMl + k * 128 + y0);
      } else {
#pragma unroll
        for (int e = 0; e < 8; ++e) { hv[e] = (f16)0.f; lv[e] = (f16)0.f; }
      }
#pragma unroll
      for (int e = 0; e < 8; ++e) {
        Ph[(lw + hk * 8 + e) * LDK + k] = hv[e];
        Pl[(lw + hk * 8 + e) * LDK + k] = lv[e];
      }
    }
  } else if (isW) {
    const float* pW = WA + n0 * 4096;
#pragma unroll
    for (int it = 0; it < 8; ++it) {
      const int t = lane + it * 64;
      const int n = t >> 2, b4 = (t & 3) * 4;
      const float4 w4 = *(const float4*)(pW + n * 32 + h * 16 + b4);
      const float vv[4] = {w4.x, w4.y, w4.z, w4.w};
#pragma unroll
      for (int r = 0; r < 4; ++r) {
        const f16 hh = (f16)vv[r];
        Ph[(lw + b4 + r) * LDK + n] = hh;
        Pl[(lw + b4 + r) * LDK + n] = (f16)(vv[r] - (float)hh);
      }
    }
  }
  __syncthreads();

#pragma unroll 1
  for (int j = 1; j <= 15; ++j) {
    const size_t nd = n0 + j;
    const int cur = j & 1;
    // W prefetch (reg-destined) FIRST, then the stage
    float4 w4s[8];
    if (isW) {
      const float* Wn = WA + nd * 4096;
#pragma unroll
      for (int nt = 0; nt < 8; ++nt)
        w4s[nt] = *(const float4*)(Wn + (nt * 16 + lr) * 32 + h * 16 + q * 4);
    }
    if (j < 15)
      pk_stage<192, 8>(MhA + (nd + 1) * 16384, MlA + (nd + 1) * 16384,
                       BstH[cur ^ 1], BstL[cur ^ 1], src, tid);
    f16x8 ah[4], al[4];
    if (isM || isW) {
#pragma unroll
      for (int kt = 0; kt < 4; ++kt)
        if (kt >= ktA0) {
          const int off = (lw + lr) * LDK + kt * 32 + q * 8;
          ah[kt] = *(const f16x8*)(Ph + off);
          al[kt] = *(const f16x8*)(Pl + off);
        }
    }
    f32x4 acc[8];
#pragma unroll
    for (int nt = 0; nt < 8; ++nt) acc[nt] = (f32x4){0.f, 0.f, 0.f, 0.f};
    if (isM || isW) {
      const int ntF = isW ? 0 : mt;
#pragma unroll
      for (int nt = 0; nt < 8; ++nt) {
        if (nt >= ntF) {
#pragma unroll
          for (int kt = 0; kt < 4; ++kt) {
            if (kt >= ktA0 && kt <= (nt >> 1)) {
              f16x8 bh, bl;
              const int j0 = kt * 4 + q;
              read_pk(BstH[cur], nt, lr, j0, bh);
              read_pk(BstL[cur], nt, lr, j0, bl);
              acc[nt] = mfma3(ah[kt], al[kt], bh, bl, acc[nt]);
            }
          }
        }
      }
    }
    // epilogue: GLOBAL stores first (cover before end-of-step drain), then P.
    if (isM) {
      f16* oMh = MhB + nd * 16384;
      f16* oMl = MlB + nd * 16384;
      if (mt & 1) {
        const int k = (mt - 1) * 16 + lr;
        const f16x4 z = {(f16)0.f, (f16)0.f, (f16)0.f, (f16)0.f};
        *(f16x4*)(oMh + k * 128 + mt * 16 + q * 4) = z;
        *(f16x4*)(oMl + k * 128 + mt * 16 + q * 4) = z;
      }
      f16x4 hv4s[8], lv4s[8];
#pragma unroll
      for (int nt = 0; nt < 8; ++nt) {
        if (nt < mt) continue;
#pragma unroll
        for (int r = 0; r < 4; ++r) {
          const float v = acc[nt][r];
          const f16 hh = (f16)v;
          hv4s[nt][r] = hh;
          lv4s[nt][r] = (f16)(v - (float)hh);
        }
        const int k = nt * 16 + lr;
        *(f16x4*)(oMh + k * 128 + mt * 16 + q * 4) = hv4s[nt];
        *(f16x4*)(oMl + k * 128 + mt * 16 + q * 4) = lv4s[nt];
      }
#pragma unroll
      for (int nt = 0; nt < 8; ++nt) {
        if (nt < mt) continue;
#pragma unroll
        for (int r = 0; r < 4; ++r) {
          Ph[(lw + q * 4 + r) * LDK + nt * 16 + lr] = hv4s[nt][r];
          Pl[(lw + q * 4 + r) * LDK + nt * 16 + lr] = lv4s[nt][r];
        }
      }
    } else if (isW) {
      float* oW = WB + nd * 4096;
      float vs[8][4];
#pragma unroll
      for (int nt = 0; nt < 8; ++nt) {
#pragma unroll
        for (int r = 0; r < 4; ++r) vs[nt][r] = acc[nt][r];
        vs[nt][0] += w4s[nt].x; vs[nt][1] += w4s[nt].y;
        vs[nt][2] += w4s[nt].z; vs[nt][3] += w4s[nt].w;
        const float4 o = {vs[nt][0], vs[nt][1], vs[nt][2], vs[nt][3]};
        *(float4*)(oW + (nt * 16 + lr) * 32 + h * 16 + q * 4) = o;
      }
#pragma unroll
      for (int nt = 0; nt < 8; ++nt) {
#pragma unroll
        for (int r = 0; r < 4; ++r) {
          const f16 hh = (f16)vs[nt][r];
          Ph[(lw + q * 4 + r) * LDK + nt * 16 + lr] = hh;
          Pl[(lw + q * 4 + r) * LDK + nt * 16 + lr] = (f16)(vs[nt][r] - (float)hh);
        }
      }
    }
    __syncthreads();
  }
}

// ---------------------------------------------------------------------------
// gscan: ASYNC serial Horner state scan over group totals (set B 16t+15).
// grid 32: g = bid&15, h = bid>>4. 256 threads. Per step: wait_vm0 (stage t,
// full-step cover) -> bar -> W(t+1) reg loads -> stage(t+1) -> frags+MFMA ->
// bar -> LDS epilogue -> bar. No global stores in loop => clean vmcnt(0).
__global__ __launch_bounds__(256) void gscan(const f16* __restrict__ MhB,
                                             const f16* __restrict__ MlB,
                                             const float* __restrict__ WB,
                                             float* __restrict__ Ef) {
  __shared__ f16 Sh[16 * LDK], Sl[16 * LDK];
  __shared__ f16 GstH[2][PKF], GstL[2][PKF];
  const int g = blockIdx.x & 15, h = blockIdx.x >> 4;
  const int tid = threadIdx.x;
  int src[6];
  pk_precompute<256, 6>(tid, src);
  const int wv = (tid >> 6) & 3;
  const int lane = tid & 63, lr = lane & 15, q = lane >> 4;
  const int nts[2] = {wv, 7 - wv};
  const int ktAmax = (7 - wv) >> 1;
  for (int t = tid; t < 16 * LDK; t += 256) { Sh[t] = (f16)0.f; Sl[t] = (f16)0.f; }
  float4 w4c[2];
  if (g > 0) {
    const float* a0 = WB + (size_t)15 * 4096;
    w4c[0] = *(const float4*)(a0 + (nts[0] * 16 + lr) * 32 + h * 16 + q * 4);
    w4c[1] = *(const float4*)(a0 + (nts[1] * 16 + lr) * 32 + h * 16 + q * 4);
    pk_stage<256, 6>(MhB + (size_t)15 * 16384, MlB + (size_t)15 * 16384,
                     GstH[0], GstL[0], src, tid);
  }
  bar_nodrain();  // S zero-init visible
#pragma unroll 1
  for (int t = 0; t < g; ++t) {
    const int cur = t & 1;
    wait_vm0();    // stage(t) complete (own); issued a full step earlier
    bar_nodrain(); // all waves' stage portions complete
    float4 w4n[2];
    if (t + 1 < g) {
      const size_t nn = (size_t)(16 * (t + 1) + 15);
      const float* an = WB + nn * 4096;
      w4n[0] = *(const float4*)(an + (nts[0] * 16 + lr) * 32 + h * 16 + q * 4);
      w4n[1] = *(const float4*)(an + (nts[1] * 16 + lr) * 32 + h * 16 + q * 4);
      pk_stage<256, 6>(MhB + nn * 16384, MlB + nn * 16384,
                       GstH[cur ^ 1], GstL[cur ^ 1], src, tid);
    }
    f16x8 ah[4], al[4];
#pragma unroll
    for (int kt = 0; kt < 4; ++kt)
      if (kt <= ktAmax) {
        const int off = lr * LDK + kt * 32 + q * 8;
        ah[kt] = *(const f16x8*)(Sh + off);
        al[kt] = *(const f16x8*)(Sl + off);
      }
    f32x4 acc[2];
#pragma unroll
    for (int ni = 0; ni < 2; ++ni) acc[ni] = (f32x4){0.f, 0.f, 0.f, 0.f};
#pragma unroll
    for (int ni = 0; ni < 2; ++ni) {
      const int nt = nts[ni];
#pragma unroll
      for (int kt = 0; kt < 4; ++kt)
        if (kt <= (nt >> 1)) {
          f16x8 bh, bl;
          const int j0 = kt * 4 + q;
          read_pk(GstH[cur], nt, lr, j0, bh);
          read_pk(GstL[cur], nt, lr, j0, bl);
          acc[ni] = mfma3(ah[kt], al[kt], bh, bl, acc[ni]);
        }
    }
    bar_nodrain();  // all S frag reads done before overwrite
#pragma unroll
    for (int ni = 0; ni < 2; ++ni) {
      const int nt = nts[ni];
      float v[4] = {acc[ni][0], acc[ni][1], acc[ni][2], acc[ni][3]};
      v[0] += w4c[ni].x; v[1] += w4c[ni].y; v[2] += w4c[ni].z; v[3] += w4c[ni].w;
#pragma unroll
      for (int r = 0; r < 4; ++r) {
        const int o = (q * 4 + r) * LDK + nt * 16 + lr;
        const f16 hh = (f16)v[r];
        Sh[o] = hh;
        Sl[o] = (f16)(v[r] - (float)hh);
      }
    }
    if (t + 1 < g) { w4c[0] = w4n[0]; w4c[1] = w4n[1]; }
    bar_nodrain();  // S writes visible for next step's frag reads
  }
  for (int t = tid; t < 2048; t += 256) {
    const int row = t & 15, n = t >> 4;
    Ef[(size_t)g * 4096 + n * 32 + h * 16 + row] =
        (float)Sh[row * LDK + n] + (float)Sl[row * LDK + n];
  }
}

// ---------------------------------------------------------------------------
// K3 h-split: grid 512 (c = bid>>1, h = bid&1), 320 thr. Async Ast[2] pipeline
// with prefetched dirs (reg loads before stage).
__global__ __launch_bounds__(320) void k3h(const float* __restrict__ A,
                                           const float* __restrict__ x,
                                           const float* __restrict__ Bv,
                                           const f16* __restrict__ MhA,
                                           const f16* __restrict__ MlA,
                                           const float* __restrict__ WA,
                                           const f16* __restrict__ MhB,
                                           const f16* __restrict__ MlB,
                                           const float* __restrict__ WB,
                                           const float* __restrict__ Ef,
                                           float* __restrict__ out) {
  __shared__ f16 Sh[16 * LDK], Sl[16 * LDK];
  __shared__ float Ast[2][9216];
  const int tid = threadIdx.x;
  const int c = blockIdx.x >> 1, h = blockIdx.x & 1;
  const int g = c >> 4, j = c & 15;
  const int lane = tid & 63, lr = lane & 15, q = lane >> 4;
  int soff[8];
  compute_soff(tid, soff);
  // dir for t4=0 (waves 0,1) FIRST, then the stage
  float dir[8];
  if (tid < 128) {
    const int ntL = tid >> 6;
    const float* p = A + (size_t)(4 * c) * 16384 + (ntL * 16 + lr) * 128 + q * 8;
    *(float4*)&dir[0] = *(const float4*)p;
    *(float4*)&dir[4] = *(const float4*)(p + 4);
  }
  issue_A(A + (size_t)(4 * c) * 16384, Ast[0], soff, tid);  // stage t4=0 -> buf0
  const float* Ew = Ef + (size_t)g * 4096;
  for (int tt = tid; tt < 2048; tt += 320) {
    const int row = tt & 15, n = tt >> 4;
    const float v = Ew[n * 32 + h * 16 + row];
    const f16 hh = (f16)v;
    Sh[row * LDK + n] = hh;
    Sl[row * LDK + n] = (f16)(v - (float)hh);
  }
  bar_nodrain();  // S init visible (stage + dirs in flight)
  if (j > 0) {
    const int nd = c - 1, jp = j - 1;
    const bool inA = (jp == 0);
    const f16* mh = (inA ? MhA : MhB) + (size_t)nd * 16384;
    const f16* ml = (inA ? MlA : MlB) + (size_t)nd * 16384;
    const float* w = (inA ? WA : WB) + (size_t)nd * 4096;
    state_step_h_b16(mh, ml, w, Sh, Sl, h);
  }
#pragma unroll 1
  for (int t4 = 0; t4 < 4; ++t4) {
    const int l = 4 * c + t4;
    const float* Anext = (t4 < 3) ? A + (size_t)(l + 1) * 16384 : nullptr;
    state_step_h_stagedA(Anext, x + l * 32, Bv + l * 128, Sh, Sl,
                         out + (size_t)l * 4096, h, Ast[t4 & 1],
                         (float*)Ast[(t4 + 1) & 1], soff, dir, Anext);
  }
}

// ---------------------------------------------------------------------------
extern "C" void kernel_launch(void* const* d_in, const int* in_sizes, int n_in,
                              void* d_out, int out_size, void* d_ws, size_t ws_size,
                              hipStream_t stream) {
  const float* x  = (const float*)d_in[0];  // (1024, 32)
  const float* A  = (const float*)d_in[1];  // (1024, 128, 128) lower-triangular
  const float* Bv = (const float*)d_in[2];  // (1024, 128)
  float* out = (float*)d_out;               // (1024, 32, 128)

  // set A: chunk units (k1 output)
  f16* MhA = (f16*)d_ws;                    // 256*16384 f16
  f16* MlA = MhA + 256 * 16384;
  float* WA = (float*)(MlA + 256 * 16384);  // 256*4096 f32
  // set B: within-group prefixes j>=1 (mscan_s output)
  f16* MhB = (f16*)(WA + 256 * 4096);
  f16* MlB = MhB + 256 * 16384;
  float* WB = (float*)(MlB + 256 * 16384);
  // entry states (f32)
  float* Ef = WB + 256 * 4096;              // 16*4096 f32; total ~42.2 MB

  k1_chunks<<<512, 320, 0, stream>>>(A, x, Bv, MhA, MlA, WA);
  mscan_s<<<64, 192, 0, stream>>>(MhA, MlA, WA, MhB, MlB, WB);
  gscan<<<32, 256, 0, stream>>>(MhB, MlB, WB, Ef);
  k3h<<<512, 320, 0, stream>>>(A, x, Bv, MhA, MlA, WA, MhB, MlB, WB, Ef, out);
}